// Round 1
// baseline (545.557 us; speedup 1.0000x reference)
//
#include <hip/hip_runtime.h>

// out[k][n][d] = x[n][d] - c[k][d]
// N=65536, K=32, D=64. Output 536.9 MB fp32 -> write-bandwidth-bound.

#define NPTS 65536
#define KC   32
#define DW   64
#define D4   (DW / 4)   // 16 float4 per row

__global__ __launch_bounds__(256) void kmeans_diff_kernel(
    const float4* __restrict__ x,     // [N, D4]
    const float4* __restrict__ c,     // [K, D4]
    float4* __restrict__ out)         // [K, N, D4]
{
    const int tid = blockIdx.x * blockDim.x + threadIdx.x;  // 0 .. N*D4-1
    const int d4  = tid & (D4 - 1);

    // Load this thread's x fragment once.
    const float4 xv = x[tid];

    const int plane = NPTS * D4;  // float4 elements per k-plane

#pragma unroll
    for (int k = 0; k < KC; ++k) {
        const float4 cv = c[k * D4 + d4];   // 256B per wave, L1 broadcast
        float4 o;
        o.x = xv.x - cv.x;
        o.y = xv.y - cv.y;
        o.z = xv.z - cv.z;
        o.w = xv.w - cv.w;
        out[k * plane + tid] = o;           // contiguous 1KiB per wave-store
    }
}

extern "C" void kernel_launch(void* const* d_in, const int* in_sizes, int n_in,
                              void* d_out, int out_size, void* d_ws, size_t ws_size,
                              hipStream_t stream) {
    const float4* x = (const float4*)d_in[0];   // input_x   [N, D]
    const float4* c = (const float4*)d_in[1];   // centroid  [K, D]
    float4* out = (float4*)d_out;               // [K, N, D]

    const int total_threads = NPTS * D4;        // 1,048,576
    const int block = 256;
    const int grid = total_threads / block;     // 4096

    kmeans_diff_kernel<<<grid, block, 0, stream>>>(x, c, out);
}